// Round 2
// baseline (441.782 us; speedup 1.0000x reference)
//
#include <hip/hip_runtime.h>

// SecondOrderFeatureInteraction: B=16384, N=32, D=128, fp32.
// out[b][p] = dot(x[b][i], x[b][j]) for strict upper triangle pairs (i<j),
// p = 31*i - i*(i-1)/2 + (j-i-1).
//
// One wave per batch; 4 waves per block (private 16KB LDS slab each, no barriers).
// Lane decomposition: chunk = lane&3 (d-chunk, interleaved d4 % 4),
//                     tj = (lane>>2)&3, ti = lane>>4  (8x8 register tile of the 32x32 Gram).
// LDS layout: float4 lds[i][qs], qs = d4 ^ (2*(i>>3))  -> 2 addrs per bank-quad = free.

#define WAVES_PER_BLOCK 4
#define F4_PER_BATCH 1024   // 32 rows * 32 float4
#define OUT_PER_BATCH 496

__global__ __launch_bounds__(256, 2)
void soi_gram_kernel(const float* __restrict__ x, float* __restrict__ out) {
    const int wave = threadIdx.x >> 6;
    const int lane = threadIdx.x & 63;
    const int b = blockIdx.x * WAVES_PER_BLOCK + wave;

    __shared__ float4 lds[WAVES_PER_BLOCK * F4_PER_BATCH];  // 64 KB
    float4* myLds = &lds[wave * F4_PER_BATCH];

    // ---------------- stage: 16 float4 per lane, coalesced, swizzled store ----------------
    const float4* xb = reinterpret_cast<const float4*>(x) + (size_t)b * F4_PER_BATCH;
#pragma unroll
    for (int k = 0; k < 16; ++k) {
        const int f4 = (k << 6) + lane;          // 0..1023, coalesced global read
        const int i  = f4 >> 5;                  // row 0..31
        const int d4 = f4 & 31;                  // float4-column 0..31
        const int qs = d4 ^ ((i >> 3) << 1);     // XOR swizzle
        myLds[i * 32 + qs] = xb[f4];
    }
    // all lanes' ds_writes must land before this wave's ds_reads (wave-private slab,
    // so a wave-level wait suffices; no __syncthreads needed)
    asm volatile("s_waitcnt lgkmcnt(0)" ::: "memory");

    // ---------------- compute: 8x8 register tile, 32 d per lane ----------------
    const int chunk = lane & 3;
    const int tj = (lane >> 2) & 3;
    const int ti = lane >> 4;
    const int arow0 = ti << 3;
    const int brow0 = tj << 3;
    const int aswz = ti << 1;
    const int bswz = tj << 1;

    float acc[8][8];
#pragma unroll
    for (int r = 0; r < 8; ++r)
#pragma unroll
        for (int c = 0; c < 8; ++c) acc[r][c] = 0.0f;

#pragma unroll
    for (int dq = 0; dq < 8; ++dq) {
        const int d4 = chunk + (dq << 2);        // interleaved d-chunks
        float4 a4[8], b4[8];
#pragma unroll
        for (int r = 0; r < 8; ++r)
            a4[r] = myLds[(arow0 + r) * 32 + (d4 ^ aswz)];
#pragma unroll
        for (int r = 0; r < 8; ++r)
            b4[r] = myLds[(brow0 + r) * 32 + (d4 ^ bswz)];
#pragma unroll
        for (int r = 0; r < 8; ++r)
#pragma unroll
            for (int c = 0; c < 8; ++c) {
                acc[r][c] += a4[r].x * b4[c].x;
                acc[r][c] += a4[r].y * b4[c].y;
                acc[r][c] += a4[r].z * b4[c].z;
                acc[r][c] += a4[r].w * b4[c].w;
            }
    }

    // ---------------- reduce over the 4 d-chunk lanes (quad-local -> DPP) ----------------
#pragma unroll
    for (int r = 0; r < 8; ++r)
#pragma unroll
        for (int c = 0; c < 8; ++c) {
            float v = acc[r][c];
            v += __shfl_xor(v, 1);
            v += __shfl_xor(v, 2);
            acc[r][c] = v;
        }

    // ---------------- write strict upper triangle ----------------
    // each chunk lane writes 2 of the tile's 8 rows; tiles with ti>tj have nothing to write
    float* outb = out + (size_t)b * OUT_PER_BATCH;
#pragma unroll
    for (int rr = 0; rr < 2; ++rr) {
        const int r = (chunk << 1) + rr;
        const int i = arow0 + r;
        const int rowOff = 31 * i - (i * (i - 1)) / 2;
#pragma unroll
        for (int c = 0; c < 8; ++c) {
            const int j = brow0 + c;
            if (j > i) outb[rowOff + (j - i - 1)] = acc[r][c];
        }
    }
}

extern "C" void kernel_launch(void* const* d_in, const int* in_sizes, int n_in,
                              void* d_out, int out_size, void* d_ws, size_t ws_size,
                              hipStream_t stream) {
    const float* x = (const float*)d_in[0];
    float* out = (float*)d_out;
    const int batch = in_sizes[0] / (32 * 128);          // 16384
    const int grid = batch / WAVES_PER_BLOCK;            // 4096
    soi_gram_kernel<<<grid, 256, 0, stream>>>(x, out);
}

// Round 3
// 434.317 us; speedup vs baseline: 1.0172x; 1.0172x over previous
//
#include <hip/hip_runtime.h>

// SecondOrderFeatureInteraction: B=16384, N=32, D=128, fp32.
// out[b][p] = dot(x[b][i], x[b][j]), i<j, p = 31*i - i*(i-1)/2 + (j-i-1).
//
// One wave per batch, 2 waves/block (32KB LDS -> 5 blocks/CU = 10 waves/CU).
// Stage: 16x global_load_lds(16B), LDS dest linear, global source pre-swizzled
//        so LDS holds float4 slot [i*32 + (d4 ^ 2*(i>>3))] = x[b][i][d4].
// Compute: lane=(chunk,tj,ti): 8x8 register tile, d-chunk = d4 % 4.
// Output: scatter 496 floats into the dead LDS slab at triangle offsets,
//         read back as 124 contiguous float4, 2 coalesced dwordx4 stores.

#define WAVES_PER_BLOCK 2
#define F4_PER_BATCH 1024   // 32 rows * 32 float4
#define OUT_PER_BATCH 496

__global__ __launch_bounds__(128)
void soi_gram_kernel(const float* __restrict__ x, float* __restrict__ out) {
    const int wave = threadIdx.x >> 6;
    const int lane = threadIdx.x & 63;
    const int b = blockIdx.x * WAVES_PER_BLOCK + wave;

    __shared__ float4 lds[WAVES_PER_BLOCK * F4_PER_BATCH];  // 32 KB
    float4* myLds = &lds[wave * F4_PER_BATCH];

    // ---------------- async stage: 16 x global_load_lds, pre-swizzled source ----------------
    const float4* xb = reinterpret_cast<const float4*>(x) + (size_t)b * F4_PER_BATCH;
    const int half = lane >> 5;      // 0/1: which row of the k-th pair this lane serves
    const int c0 = lane & 31;        // stored column for this lane (linear LDS dest)
#pragma unroll
    for (int k = 0; k < 16; ++k) {
        const int i = 2 * k + half;                       // row 0..31
        const int src = i * 32 + (c0 ^ ((i >> 3) << 1));  // inverse-swizzled source column
        __builtin_amdgcn_global_load_lds(
            (const __attribute__((address_space(1))) void*)(xb + src),
            (__attribute__((address_space(3))) void*)(myLds + k * 64),
            16, 0, 0);
    }
    asm volatile("s_waitcnt vmcnt(0)" ::: "memory");

    // ---------------- compute: 8x8 register tile, 32 d per lane ----------------
    const int chunk = lane & 3;
    const int tj = (lane >> 2) & 3;
    const int ti = lane >> 4;
    const int arow0 = ti << 3;
    const int brow0 = tj << 3;
    const int aswz = ti << 1;
    const int bswz = tj << 1;

    float acc[8][8];
#pragma unroll
    for (int r = 0; r < 8; ++r)
#pragma unroll
        for (int c = 0; c < 8; ++c) acc[r][c] = 0.0f;

#pragma unroll
    for (int dq = 0; dq < 8; ++dq) {
        const int d4 = chunk + (dq << 2);        // interleaved d-chunks
        float4 a4[8], b4[8];
#pragma unroll
        for (int r = 0; r < 8; ++r)
            a4[r] = myLds[(arow0 + r) * 32 + (d4 ^ aswz)];
#pragma unroll
        for (int r = 0; r < 8; ++r)
            b4[r] = myLds[(brow0 + r) * 32 + (d4 ^ bswz)];
#pragma unroll
        for (int r = 0; r < 8; ++r)
#pragma unroll
            for (int c = 0; c < 8; ++c) {
                acc[r][c] += a4[r].x * b4[c].x;
                acc[r][c] += a4[r].y * b4[c].y;
                acc[r][c] += a4[r].z * b4[c].z;
                acc[r][c] += a4[r].w * b4[c].w;
            }
    }

    // ---------------- reduce over the 4 d-chunk lanes (quad-local) ----------------
#pragma unroll
    for (int r = 0; r < 8; ++r)
#pragma unroll
        for (int c = 0; c < 8; ++c) {
            float v = acc[r][c];
            v += __shfl_xor(v, 1);
            v += __shfl_xor(v, 2);
            acc[r][c] = v;
        }

    // ---------------- pack triangle into LDS (slab is dead now), then coalesced store ----------------
    float* myLdsF = reinterpret_cast<float*>(myLds);
#pragma unroll
    for (int rr = 0; rr < 2; ++rr) {
        const int r = (chunk << 1) + rr;         // each quad lane owns 2 of the tile's 8 rows
        const int i = arow0 + r;
        const int base = 31 * i - (i * (i - 1)) / 2 - i - 1;   // p = base + j
#pragma unroll
        for (int c = 0; c < 8; ++c) {
            const int j = brow0 + c;
            if (j > i) myLdsF[base + j] = acc[r][c];
        }
    }
    asm volatile("s_waitcnt lgkmcnt(0)" ::: "memory");

    const float4* packed = reinterpret_cast<const float4*>(myLdsF);
    float4* outb = reinterpret_cast<float4*>(out + (size_t)b * OUT_PER_BATCH);  // 496 % 4 == 0
    outb[lane] = packed[lane];                   // f4 0..63
    if (lane < 60) outb[64 + lane] = packed[64 + lane];  // f4 64..123
}

extern "C" void kernel_launch(void* const* d_in, const int* in_sizes, int n_in,
                              void* d_out, int out_size, void* d_ws, size_t ws_size,
                              hipStream_t stream) {
    const float* x = (const float*)d_in[0];
    float* out = (float*)d_out;
    const int batch = in_sizes[0] / (32 * 128);          // 16384
    const int grid = batch / WAVES_PER_BLOCK;            // 8192
    soi_gram_kernel<<<grid, 128, 0, stream>>>(x, out);
}